// Round 1
// baseline (117.211 us; speedup 1.0000x reference)
//
#include <hip/hip_runtime.h>
#include <hip/hip_bf16.h>
#include <math.h>

#define VOCAB 50257
#define D 512
#define INV_SMOOTH 5.0f

// One wave (64 lanes) per cache row: coalesced float4 loads, wave-reduce the
// squared distance, lane 0 computes exp(dist/smooth) and scatter-adds.
__global__ void dist_scatter_kernel(const float* __restrict__ cache_h,
                                    const float* __restrict__ h_t,
                                    const int* __restrict__ word_ids,
                                    float* __restrict__ bins,
                                    int n_rows) {
    const int lane    = threadIdx.x & 63;
    const int wave    = (int)((blockIdx.x * blockDim.x + threadIdx.x) >> 6);
    const int n_waves = (int)((gridDim.x * blockDim.x) >> 6);

    // h_t is tiny (2 KiB) — cached broadcast reads
    const float4* ht4 = reinterpret_cast<const float4*>(h_t);
    const float4 b0 = ht4[lane];
    const float4 b1 = ht4[lane + 64];

    for (int row = wave; row < n_rows; row += n_waves) {
        const float4* r4 = reinterpret_cast<const float4*>(cache_h + (size_t)row * D);
        float4 a0 = r4[lane];        // elements [0,256)
        float4 a1 = r4[lane + 64];   // elements [256,512)
        float dx, s = 0.0f;
        dx = a0.x - b0.x; s = fmaf(dx, dx, s);
        dx = a0.y - b0.y; s = fmaf(dx, dx, s);
        dx = a0.z - b0.z; s = fmaf(dx, dx, s);
        dx = a0.w - b0.w; s = fmaf(dx, dx, s);
        dx = a1.x - b1.x; s = fmaf(dx, dx, s);
        dx = a1.y - b1.y; s = fmaf(dx, dx, s);
        dx = a1.z - b1.z; s = fmaf(dx, dx, s);
        dx = a1.w - b1.w; s = fmaf(dx, dx, s);
        #pragma unroll
        for (int off = 32; off > 0; off >>= 1)
            s += __shfl_xor(s, off, 64);
        if (lane == 0) {
            float kern = expf(sqrtf(s) * INV_SMOOTH);
            atomicAdd(&bins[word_ids[row]], kern);
        }
    }
}

// Max over bins (all >= 0, so uint bit-pattern atomicMax is order-preserving)
__global__ void max_kernel(const float* __restrict__ bins,
                           unsigned int* __restrict__ maxbits) {
    float m = 0.0f;
    for (int i = blockIdx.x * blockDim.x + threadIdx.x; i < VOCAB;
         i += gridDim.x * blockDim.x)
        m = fmaxf(m, bins[i]);
    #pragma unroll
    for (int off = 32; off > 0; off >>= 1)
        m = fmaxf(m, __shfl_xor(m, off, 64));
    __shared__ float sm[16];
    const int lane = threadIdx.x & 63, w = threadIdx.x >> 6;
    if (lane == 0) sm[w] = m;
    __syncthreads();
    if (threadIdx.x == 0) {
        float mm = sm[0];
        for (int i = 1; i < (int)(blockDim.x >> 6); ++i) mm = fmaxf(mm, sm[i]);
        atomicMax(maxbits, __float_as_uint(mm));
    }
}

__global__ void sumexp_kernel(const float* __restrict__ bins,
                              const unsigned int* __restrict__ maxbits,
                              float* __restrict__ sum) {
    const float mv = __uint_as_float(*maxbits);
    float s = 0.0f;
    for (int i = blockIdx.x * blockDim.x + threadIdx.x; i < VOCAB;
         i += gridDim.x * blockDim.x)
        s += expf(bins[i] - mv);
    #pragma unroll
    for (int off = 32; off > 0; off >>= 1)
        s += __shfl_xor(s, off, 64);
    __shared__ float sm[16];
    const int lane = threadIdx.x & 63, w = threadIdx.x >> 6;
    if (lane == 0) sm[w] = s;
    __syncthreads();
    if (threadIdx.x == 0) {
        float ss = sm[0];
        for (int i = 1; i < (int)(blockDim.x >> 6); ++i) ss += sm[i];
        atomicAdd(sum, ss);
    }
}

__global__ void out_kernel(const float* __restrict__ bins,
                           const unsigned int* __restrict__ maxbits,
                           const float* __restrict__ sum,
                           float* __restrict__ out) {
    const float lse = __uint_as_float(*maxbits) + logf(*sum);
    const int i = blockIdx.x * blockDim.x + threadIdx.x;
    if (i < VOCAB) out[i] = bins[i] - lse;
}

extern "C" void kernel_launch(void* const* d_in, const int* in_sizes, int n_in,
                              void* d_out, int out_size, void* d_ws, size_t ws_size,
                              hipStream_t stream) {
    const float* h_t     = (const float*)d_in[0];
    const float* cache_h = (const float*)d_in[1];
    const int*   word_ids = (const int*)d_in[2];
    float* out = (float*)d_out;

    const int n_rows = in_sizes[2];  // N_CACHE

    float* bins = (float*)d_ws;                       // [VOCAB]
    unsigned int* maxbits = (unsigned int*)(bins + VOCAB);
    float* sum = (float*)(bins + VOCAB + 1);

    // zero bins + max + sum every call (harness poisons ws with 0xAA)
    hipMemsetAsync(d_ws, 0, (VOCAB + 2) * sizeof(float), stream);

    // 2048 blocks x 256 threads = 8192 waves, grid-stride over rows
    dist_scatter_kernel<<<2048, 256, 0, stream>>>(cache_h, h_t, word_ids, bins, n_rows);
    max_kernel<<<128, 256, 0, stream>>>(bins, maxbits);
    sumexp_kernel<<<128, 256, 0, stream>>>(bins, maxbits, sum);
    out_kernel<<<(VOCAB + 255) / 256, 256, 0, stream>>>(bins, maxbits, sum, out);
}